// Round 2
// baseline (582.365 us; speedup 1.0000x reference)
//
#include <hip/hip_runtime.h>

#define N_NODES 50000
#define N_EDGES 800000

// ---------------- CSR build ----------------

__global__ __launch_bounds__(256) void zero_counts(int* __restrict__ counts) {
    int i = blockIdx.x * 256 + threadIdx.x;
    if (i < N_NODES) counts[i] = 0;
}

__global__ __launch_bounds__(256) void hist_k(const int* __restrict__ ei, int* __restrict__ counts) {
    int e = blockIdx.x * 256 + threadIdx.x;
    if (e < N_EDGES) atomicAdd(&counts[ei[N_EDGES + e]], 1);
}

// block-level inclusive scan over 1024 elems -> exclusive start[], block sums
__global__ __launch_bounds__(1024) void scan1_k(const int* __restrict__ counts,
                                                int* __restrict__ start,
                                                int* __restrict__ bsums) {
    __shared__ int s[1024];
    int i = blockIdx.x * 1024 + threadIdx.x;
    int x = (i < N_NODES) ? counts[i] : 0;
    s[threadIdx.x] = x;
    __syncthreads();
    for (int off = 1; off < 1024; off <<= 1) {
        int v = (threadIdx.x >= off) ? s[threadIdx.x - off] : 0;
        __syncthreads();
        s[threadIdx.x] += v;
        __syncthreads();
    }
    if (i < N_NODES) start[i] = s[threadIdx.x] - x;
    if (threadIdx.x == 1023) bsums[blockIdx.x] = s[1023];
}

__global__ void scan2_k(int* __restrict__ bsums, int nblocks) {
    if (threadIdx.x == 0 && blockIdx.x == 0) {
        int run = 0;
        for (int b = 0; b < nblocks; ++b) {
            int t = bsums[b];
            bsums[b] = run;
            run += t;
        }
    }
}

__global__ __launch_bounds__(256) void scan3_k(int* __restrict__ start,
                                               int* __restrict__ cursor,
                                               const int* __restrict__ bsums) {
    int i = blockIdx.x * 256 + threadIdx.x;
    if (i < N_NODES) {
        int v = start[i] + bsums[i >> 10];
        start[i] = v;
        cursor[i] = v;
    }
}

// per edge: compute c[e,b] = sum_r ea[e,r]*att[r,b] for BOTH layers, scatter into CSR slots
__global__ __launch_bounds__(256) void scatter_k(const int* __restrict__ ei,
                                                 const float* __restrict__ ea,
                                                 const float* __restrict__ att,   // [2,8,4]
                                                 int* __restrict__ cursor,
                                                 int* __restrict__ src_s,
                                                 float4* __restrict__ c0s,
                                                 float4* __restrict__ c1s) {
    int e = blockIdx.x * 256 + threadIdx.x;
    if (e >= N_EDGES) return;
    int src = ei[e];
    int dst = ei[N_EDGES + e];

    const float4* eav = (const float4*)(ea + (size_t)e * 8);
    float4 a0 = eav[0], a1 = eav[1];
    float ev[8] = {a0.x, a0.y, a0.z, a0.w, a1.x, a1.y, a1.z, a1.w};

    float4 c0 = make_float4(0.f, 0.f, 0.f, 0.f);
    float4 c1 = make_float4(0.f, 0.f, 0.f, 0.f);
    const float4* att0 = (const float4*)att;        // [8] rows of 4
    const float4* att1 = (const float4*)(att + 32);
    #pragma unroll
    for (int r = 0; r < 8; ++r) {
        float4 w0 = att0[r];
        float4 w1 = att1[r];
        c0.x = fmaf(ev[r], w0.x, c0.x); c0.y = fmaf(ev[r], w0.y, c0.y);
        c0.z = fmaf(ev[r], w0.z, c0.z); c0.w = fmaf(ev[r], w0.w, c0.w);
        c1.x = fmaf(ev[r], w1.x, c1.x); c1.y = fmaf(ev[r], w1.y, c1.y);
        c1.z = fmaf(ev[r], w1.z, c1.z); c1.w = fmaf(ev[r], w1.w, c1.w);
    }
    int pos = atomicAdd(&cursor[dst], 1);
    src_s[pos] = src;
    c0s[pos] = c0;
    c1s[pos] = c1;
}

// ---------------- per-layer kernels ----------------

// one wave per dst node; lane = channel. y[node][b*64+lane] = sum_e c[e,b]*h[src][lane]
__global__ __launch_bounds__(256) void agg_k(const int* __restrict__ start,
                                             const int* __restrict__ counts,
                                             const int* __restrict__ src_s,
                                             const float4* __restrict__ cs,
                                             const float* __restrict__ h,
                                             float* __restrict__ y) {
    int node = blockIdx.x * 4 + (threadIdx.x >> 6);
    int lane = threadIdx.x & 63;
    if (node >= N_NODES) return;
    int s = start[node];
    int cnt = counts[node];

    float y0 = 0.f, y1 = 0.f, y2 = 0.f, y3 = 0.f;
    for (int j = 0; j < cnt; ++j) {
        int e = s + j;
        int sv = src_s[e];          // broadcast
        float4 c = cs[e];           // broadcast
        float hv = h[(size_t)sv * 64 + lane];  // 256B coalesced gather
        y0 = fmaf(c.x, hv, y0);
        y1 = fmaf(c.y, hv, y1);
        y2 = fmaf(c.z, hv, y2);
        y3 = fmaf(c.w, hv, y3);
    }
    float* yr = y + (size_t)node * 256;
    yr[lane]       = y0;
    yr[64 + lane]  = y1;
    yr[128 + lane] = y2;
    yr[192 + lane] = y3;
}

// out[n][o] = sum_{k<256} y[n][k]*B[k][o] + sum_{k<64} h[n][k]*root[k][o] + bias[o]
// B = basis layer slice viewed as [256][64] (basis is [4][64][64] row-major = exactly that)
__global__ __launch_bounds__(256) void gemm_k(const float* __restrict__ y,
                                              const float* __restrict__ h,
                                              const float* __restrict__ B,
                                              const float* __restrict__ root,
                                              const float* __restrict__ bias,
                                              float* __restrict__ out,
                                              int relu) {
    __shared__ float4 ys4[32 * 64];  // 32 rows x 256 floats
    __shared__ float4 hs4[32 * 16];  // 32 rows x 64 floats
    const int tid = threadIdx.x;
    const int tx = tid & 63;
    const int wv = tid >> 6;
    const int n0 = blockIdx.x * 32;

    const float4* yg = (const float4*)(y + (size_t)n0 * 256);
    for (int i = tid; i < 2048; i += 256) {
        int row = i >> 6;
        ys4[i] = (n0 + row < N_NODES) ? yg[i] : make_float4(0.f, 0.f, 0.f, 0.f);
    }
    const float4* hg = (const float4*)(h + (size_t)n0 * 64);
    for (int i = tid; i < 512; i += 256) {
        int row = i >> 4;
        hs4[i] = (n0 + row < N_NODES) ? hg[i] : make_float4(0.f, 0.f, 0.f, 0.f);
    }
    __syncthreads();

    float acc[8] = {0.f, 0.f, 0.f, 0.f, 0.f, 0.f, 0.f, 0.f};
    const int rbase = wv * 8;

    // y @ B : k in [0,256) in float4 chunks
    for (int k4 = 0; k4 < 64; ++k4) {
        float w0 = B[(k4 * 4 + 0) * 64 + tx];
        float w1 = B[(k4 * 4 + 1) * 64 + tx];
        float w2 = B[(k4 * 4 + 2) * 64 + tx];
        float w3 = B[(k4 * 4 + 3) * 64 + tx];
        #pragma unroll
        for (int r = 0; r < 8; ++r) {
            float4 yv = ys4[(rbase + r) * 64 + k4];  // ds_read_b128 broadcast
            acc[r] = fmaf(yv.x, w0, acc[r]);
            acc[r] = fmaf(yv.y, w1, acc[r]);
            acc[r] = fmaf(yv.z, w2, acc[r]);
            acc[r] = fmaf(yv.w, w3, acc[r]);
        }
    }
    // h @ root : k in [0,64)
    for (int k4 = 0; k4 < 16; ++k4) {
        float w0 = root[(k4 * 4 + 0) * 64 + tx];
        float w1 = root[(k4 * 4 + 1) * 64 + tx];
        float w2 = root[(k4 * 4 + 2) * 64 + tx];
        float w3 = root[(k4 * 4 + 3) * 64 + tx];
        #pragma unroll
        for (int r = 0; r < 8; ++r) {
            float4 hv = hs4[(rbase + r) * 16 + k4];
            acc[r] = fmaf(hv.x, w0, acc[r]);
            acc[r] = fmaf(hv.y, w1, acc[r]);
            acc[r] = fmaf(hv.z, w2, acc[r]);
            acc[r] = fmaf(hv.w, w3, acc[r]);
        }
    }

    float bv = bias[tx];
    #pragma unroll
    for (int r = 0; r < 8; ++r) {
        int n = n0 + rbase + r;
        if (n < N_NODES) {
            float v = acc[r] + bv;
            if (relu) v = fmaxf(v, 0.f);
            out[(size_t)n * 64 + tx] = v;
        }
    }
}

// ---------------- launch ----------------

extern "C" void kernel_launch(void* const* d_in, const int* in_sizes, int n_in,
                              void* d_out, int out_size, void* d_ws, size_t ws_size,
                              hipStream_t stream) {
    const float* x     = (const float*)d_in[0];
    const int*   ei    = (const int*)d_in[1];
    const float* ea    = (const float*)d_in[2];
    const float* basis = (const float*)d_in[3];  // [2,4,64,64]
    const float* att   = (const float*)d_in[4];  // [2,8,4]
    const float* root  = (const float*)d_in[5];  // [2,64,64]
    const float* bias  = (const float*)d_in[6];  // [2,64]
    float* out = (float*)d_out;

    char* p = (char*)d_ws;
    float*  y      = (float*)p;   p += (size_t)N_NODES * 256 * 4;  // 51.2 MB
    int*    src_s  = (int*)p;     p += (size_t)N_EDGES * 4;        //  3.2 MB
    float4* c0s    = (float4*)p;  p += (size_t)N_EDGES * 16;       // 12.8 MB
    float4* c1s    = (float4*)p;  p += (size_t)N_EDGES * 16;       // 12.8 MB
    int*    counts = (int*)p;     p += (size_t)N_NODES * 4;
    int*    start  = (int*)p;     p += (size_t)N_NODES * 4;
    int*    cursor = (int*)p;     p += (size_t)N_NODES * 4;
    int*    bsums  = (int*)p;     p += 64 * 4;

    float* h1 = out;  // intermediate layer-0 output lives in d_out; overwritten by final gemm

    const int scan_blocks = (N_NODES + 1023) / 1024;  // 49

    // CSR build (once per call; both layers' edge coefficients precomputed)
    zero_counts<<<(N_NODES + 255) / 256, 256, 0, stream>>>(counts);
    hist_k<<<(N_EDGES + 255) / 256, 256, 0, stream>>>(ei, counts);
    scan1_k<<<scan_blocks, 1024, 0, stream>>>(counts, start, bsums);
    scan2_k<<<1, 64, 0, stream>>>(bsums, scan_blocks);
    scan3_k<<<(N_NODES + 255) / 256, 256, 0, stream>>>(start, cursor, bsums);
    scatter_k<<<(N_EDGES + 255) / 256, 256, 0, stream>>>(ei, ea, att, cursor, src_s, c0s, c1s);

    dim3 agg_grid((N_NODES + 3) / 4);
    dim3 gemm_grid((N_NODES + 31) / 32);

    // ---- layer 0: x -> h1 (relu) ----
    agg_k<<<agg_grid, 256, 0, stream>>>(start, counts, src_s, c0s, x, y);
    gemm_k<<<gemm_grid, 256, 0, stream>>>(y, x, basis, root, bias, h1, 1);

    // ---- layer 1: h1 -> out ----
    agg_k<<<agg_grid, 256, 0, stream>>>(start, counts, src_s, c1s, h1, y);
    gemm_k<<<gemm_grid, 256, 0, stream>>>(y, h1, basis + 4 * 4096, root + 4096, bias + 64, out, 0);
}

// Round 3
// 377.737 us; speedup vs baseline: 1.5417x; 1.5417x over previous
//
#include <hip/hip_runtime.h>

#define N_NODES 50000
#define N_EDGES 800000

// ---------------- CSR build ----------------

__global__ __launch_bounds__(256) void zero_counts(int* __restrict__ counts) {
    int i = blockIdx.x * 256 + threadIdx.x;
    if (i < N_NODES) counts[i] = 0;
}

__global__ __launch_bounds__(256) void hist_k(const int* __restrict__ ei, int* __restrict__ counts) {
    int e = blockIdx.x * 256 + threadIdx.x;
    if (e < N_EDGES) atomicAdd(&counts[ei[N_EDGES + e]], 1);
}

__global__ __launch_bounds__(1024) void scan1_k(const int* __restrict__ counts,
                                                int* __restrict__ start,
                                                int* __restrict__ bsums) {
    __shared__ int s[1024];
    int i = blockIdx.x * 1024 + threadIdx.x;
    int x = (i < N_NODES) ? counts[i] : 0;
    s[threadIdx.x] = x;
    __syncthreads();
    for (int off = 1; off < 1024; off <<= 1) {
        int v = (threadIdx.x >= off) ? s[threadIdx.x - off] : 0;
        __syncthreads();
        s[threadIdx.x] += v;
        __syncthreads();
    }
    if (i < N_NODES) start[i] = s[threadIdx.x] - x;
    if (threadIdx.x == 1023) bsums[blockIdx.x] = s[1023];
}

__global__ void scan2_k(int* __restrict__ bsums, int nblocks) {
    if (threadIdx.x == 0 && blockIdx.x == 0) {
        int run = 0;
        for (int b = 0; b < nblocks; ++b) {
            int t = bsums[b];
            bsums[b] = run;
            run += t;
        }
    }
}

__global__ __launch_bounds__(256) void scan3_k(int* __restrict__ start,
                                               int* __restrict__ cursor,
                                               const int* __restrict__ bsums) {
    int i = blockIdx.x * 256 + threadIdx.x;
    if (i < N_NODES) {
        int v = start[i] + bsums[i >> 10];
        start[i] = v;
        cursor[i] = v;
    }
}

__global__ __launch_bounds__(256) void scatter_k(const int* __restrict__ ei,
                                                 const float* __restrict__ ea,
                                                 const float* __restrict__ att,   // [2,8,4]
                                                 int* __restrict__ cursor,
                                                 int* __restrict__ src_s,
                                                 float4* __restrict__ c0s,
                                                 float4* __restrict__ c1s) {
    int e = blockIdx.x * 256 + threadIdx.x;
    if (e >= N_EDGES) return;
    int src = ei[e];
    int dst = ei[N_EDGES + e];

    const float4* eav = (const float4*)(ea + (size_t)e * 8);
    float4 a0 = eav[0], a1 = eav[1];
    float ev[8] = {a0.x, a0.y, a0.z, a0.w, a1.x, a1.y, a1.z, a1.w};

    float4 c0 = make_float4(0.f, 0.f, 0.f, 0.f);
    float4 c1 = make_float4(0.f, 0.f, 0.f, 0.f);
    const float4* att0 = (const float4*)att;
    const float4* att1 = (const float4*)(att + 32);
    #pragma unroll
    for (int r = 0; r < 8; ++r) {
        float4 w0 = att0[r];
        float4 w1 = att1[r];
        c0.x = fmaf(ev[r], w0.x, c0.x); c0.y = fmaf(ev[r], w0.y, c0.y);
        c0.z = fmaf(ev[r], w0.z, c0.z); c0.w = fmaf(ev[r], w0.w, c0.w);
        c1.x = fmaf(ev[r], w1.x, c1.x); c1.y = fmaf(ev[r], w1.y, c1.y);
        c1.z = fmaf(ev[r], w1.z, c1.z); c1.w = fmaf(ev[r], w1.w, c1.w);
    }
    int pos = atomicAdd(&cursor[dst], 1);
    src_s[pos] = src;
    c0s[pos] = c0;
    c1s[pos] = c1;
}

// ---------------- per-layer kernels ----------------

// one wave per dst node; lane = channel. y[node][b*64+lane] = sum_e c[e,b]*h[src][lane]
__global__ __launch_bounds__(256) void agg_k(const int* __restrict__ start,
                                             const int* __restrict__ counts,
                                             const int* __restrict__ src_s,
                                             const float4* __restrict__ cs,
                                             const float* __restrict__ h,
                                             float* __restrict__ y) {
    int node = blockIdx.x * 4 + (threadIdx.x >> 6);
    int lane = threadIdx.x & 63;
    if (node >= N_NODES) return;
    int s = start[node];
    int cnt = counts[node];

    float y0 = 0.f, y1 = 0.f, y2 = 0.f, y3 = 0.f;
    int j = 0;
    for (; j + 1 < cnt; j += 2) {
        int e0 = s + j, e1 = s + j + 1;
        int sv0 = src_s[e0];
        int sv1 = src_s[e1];
        float4 ca = cs[e0];
        float4 cb = cs[e1];
        float ha = h[(size_t)sv0 * 64 + lane];
        float hb = h[(size_t)sv1 * 64 + lane];
        y0 = fmaf(ca.x, ha, y0); y1 = fmaf(ca.y, ha, y1);
        y2 = fmaf(ca.z, ha, y2); y3 = fmaf(ca.w, ha, y3);
        y0 = fmaf(cb.x, hb, y0); y1 = fmaf(cb.y, hb, y1);
        y2 = fmaf(cb.z, hb, y2); y3 = fmaf(cb.w, hb, y3);
    }
    if (j < cnt) {
        int e = s + j;
        int sv = src_s[e];
        float4 c = cs[e];
        float hv = h[(size_t)sv * 64 + lane];
        y0 = fmaf(c.x, hv, y0); y1 = fmaf(c.y, hv, y1);
        y2 = fmaf(c.z, hv, y2); y3 = fmaf(c.w, hv, y3);
    }
    float* yr = y + (size_t)node * 256;
    yr[lane]       = y0;
    yr[64 + lane]  = y1;
    yr[128 + lane] = y2;
    yr[192 + lane] = y3;
}

// Register-tiled fp32 GEMM: out[64x64 tile] = y(K=256)@B + h(K=64)@root + bias [, relu]
// 256 threads, each computes 4 rows x 4 cols. K staged via LDS in 16-chunks.
__global__ __launch_bounds__(256) void gemm_k(const float* __restrict__ y,
                                              const float* __restrict__ h,
                                              const float* __restrict__ B,
                                              const float* __restrict__ root,
                                              const float* __restrict__ bias,
                                              float* __restrict__ out,
                                              int relu) {
    __shared__ float As[16][68];   // k-major A tile, +4 pad (keeps float4 align, breaks conflicts)
    __shared__ float Bs[16][64];   // k-major B tile

    const int tid = threadIdx.x;
    const int tx = tid & 15;       // output col group (4 cols)
    const int ty = tid >> 4;       // output row group (4 rows)
    const int n0 = blockIdx.x * 64;

    // staging coords for A: row m = tid>>2 (0..63), float4 k-offset c = tid&3 (0..3)
    const int sm = tid >> 2;
    const int sc = tid & 3;
    // staging coords for B: k row kk = tid>>4 (0..15), col group nn = tid&15
    const int skk = tid >> 4;
    const int snn = tid & 15;

    float acc[4][4];
    #pragma unroll
    for (int i = 0; i < 4; ++i)
        #pragma unroll
        for (int jj = 0; jj < 4; ++jj) acc[i][jj] = 0.f;

    const float4 z4 = make_float4(0.f, 0.f, 0.f, 0.f);

    // two phases: (y, B, K=256) then (h, root, K=64)
    #pragma unroll 1
    for (int phase = 0; phase < 2; ++phase) {
        const float* Aptr = phase ? h : y;
        const float* Wptr = phase ? root : B;
        const int lda = phase ? 64 : 256;
        const int nchunks = phase ? 4 : 16;

        #pragma unroll 1
        for (int ch = 0; ch < nchunks; ++ch) {
            const int kc = ch * 16;
            __syncthreads();
            // stage A (transpose to k-major)
            {
                int n = n0 + sm;
                float4 av = (n < N_NODES)
                    ? *(const float4*)(Aptr + (size_t)n * lda + kc + sc * 4) : z4;
                As[sc * 4 + 0][sm] = av.x;
                As[sc * 4 + 1][sm] = av.y;
                As[sc * 4 + 2][sm] = av.z;
                As[sc * 4 + 3][sm] = av.w;
            }
            // stage W
            {
                float4 wv = *(const float4*)(Wptr + (size_t)(kc + skk) * 64 + snn * 4);
                *(float4*)&Bs[skk][snn * 4] = wv;
            }
            __syncthreads();

            #pragma unroll
            for (int k = 0; k < 16; ++k) {
                float4 a = *(const float4*)&As[k][ty * 4];
                float4 b = *(const float4*)&Bs[k][tx * 4];
                float af[4] = {a.x, a.y, a.z, a.w};
                float bf[4] = {b.x, b.y, b.z, b.w};
                #pragma unroll
                for (int i = 0; i < 4; ++i)
                    #pragma unroll
                    for (int jj = 0; jj < 4; ++jj)
                        acc[i][jj] = fmaf(af[i], bf[jj], acc[i][jj]);
            }
        }
    }

    float4 bv = *(const float4*)(bias + tx * 4);
    float bf[4] = {bv.x, bv.y, bv.z, bv.w};
    #pragma unroll
    for (int i = 0; i < 4; ++i) {
        int n = n0 + ty * 4 + i;
        if (n < N_NODES) {
            float4 o;
            o.x = acc[i][0] + bf[0];
            o.y = acc[i][1] + bf[1];
            o.z = acc[i][2] + bf[2];
            o.w = acc[i][3] + bf[3];
            if (relu) {
                o.x = fmaxf(o.x, 0.f); o.y = fmaxf(o.y, 0.f);
                o.z = fmaxf(o.z, 0.f); o.w = fmaxf(o.w, 0.f);
            }
            *(float4*)(out + (size_t)n * 64 + tx * 4) = o;
        }
    }
}

// ---------------- launch ----------------

extern "C" void kernel_launch(void* const* d_in, const int* in_sizes, int n_in,
                              void* d_out, int out_size, void* d_ws, size_t ws_size,
                              hipStream_t stream) {
    const float* x     = (const float*)d_in[0];
    const int*   ei    = (const int*)d_in[1];
    const float* ea    = (const float*)d_in[2];
    const float* basis = (const float*)d_in[3];  // [2,4,64,64]
    const float* att   = (const float*)d_in[4];  // [2,8,4]
    const float* root  = (const float*)d_in[5];  // [2,64,64]
    const float* bias  = (const float*)d_in[6];  // [2,64]
    float* out = (float*)d_out;

    char* p = (char*)d_ws;
    float*  y      = (float*)p;   p += (size_t)N_NODES * 256 * 4;  // 51.2 MB
    int*    src_s  = (int*)p;     p += (size_t)N_EDGES * 4;        //  3.2 MB
    float4* c0s    = (float4*)p;  p += (size_t)N_EDGES * 16;       // 12.8 MB
    float4* c1s    = (float4*)p;  p += (size_t)N_EDGES * 16;       // 12.8 MB
    int*    counts = (int*)p;     p += (size_t)N_NODES * 4;
    int*    start  = (int*)p;     p += (size_t)N_NODES * 4;
    int*    cursor = (int*)p;     p += (size_t)N_NODES * 4;
    int*    bsums  = (int*)p;     p += 64 * 4;

    float* h1 = out;  // layer-0 output lives in d_out; overwritten by final gemm

    const int scan_blocks = (N_NODES + 1023) / 1024;  // 49

    zero_counts<<<(N_NODES + 255) / 256, 256, 0, stream>>>(counts);
    hist_k<<<(N_EDGES + 255) / 256, 256, 0, stream>>>(ei, counts);
    scan1_k<<<scan_blocks, 1024, 0, stream>>>(counts, start, bsums);
    scan2_k<<<1, 64, 0, stream>>>(bsums, scan_blocks);
    scan3_k<<<(N_NODES + 255) / 256, 256, 0, stream>>>(start, cursor, bsums);
    scatter_k<<<(N_EDGES + 255) / 256, 256, 0, stream>>>(ei, ea, att, cursor, src_s, c0s, c1s);

    dim3 agg_grid((N_NODES + 3) / 4);
    dim3 gemm_grid((N_NODES + 63) / 64);

    // ---- layer 0: x -> h1 (relu) ----
    agg_k<<<agg_grid, 256, 0, stream>>>(start, counts, src_s, c0s, x, y);
    gemm_k<<<gemm_grid, 256, 0, stream>>>(y, x, basis, root, bias, h1, 1);

    // ---- layer 1: h1 -> out ----
    agg_k<<<agg_grid, 256, 0, stream>>>(start, counts, src_s, c1s, h1, y);
    gemm_k<<<gemm_grid, 256, 0, stream>>>(y, h1, basis + 4 * 4096, root + 4096, bias + 64, out, 0);
}

// Round 4
// 355.809 us; speedup vs baseline: 1.6367x; 1.0616x over previous
//
#include <hip/hip_runtime.h>

#define N_NODES 50000
#define N_EDGES 800000

typedef unsigned int uint;
typedef unsigned short ushort;

__device__ __forceinline__ ushort f2bf(float f) {
    uint u = __builtin_bit_cast(uint, f);
    u += 0x7fffu + ((u >> 16) & 1u);      // round-to-nearest-even
    return (ushort)(u >> 16);
}
__device__ __forceinline__ float bf2f(ushort h) {
    uint u = ((uint)h) << 16;
    return __builtin_bit_cast(float, u);
}
__device__ __forceinline__ uint pack2(float a, float b) {
    return (uint)f2bf(a) | ((uint)f2bf(b) << 16);
}

// ---------------- CSR build ----------------

__global__ __launch_bounds__(256) void zero_counts(int* __restrict__ counts) {
    int i = blockIdx.x * 256 + threadIdx.x;
    if (i < N_NODES) counts[i] = 0;
}

__global__ __launch_bounds__(256) void hist_k(const int* __restrict__ ei, int* __restrict__ counts) {
    int e = blockIdx.x * 256 + threadIdx.x;
    if (e < N_EDGES) atomicAdd(&counts[ei[N_EDGES + e]], 1);
}

__global__ __launch_bounds__(1024) void scan1_k(const int* __restrict__ counts,
                                                int* __restrict__ start,
                                                int* __restrict__ bsums) {
    __shared__ int s[1024];
    int i = blockIdx.x * 1024 + threadIdx.x;
    int x = (i < N_NODES) ? counts[i] : 0;
    s[threadIdx.x] = x;
    __syncthreads();
    for (int off = 1; off < 1024; off <<= 1) {
        int v = (threadIdx.x >= off) ? s[threadIdx.x - off] : 0;
        __syncthreads();
        s[threadIdx.x] += v;
        __syncthreads();
    }
    if (i < N_NODES) start[i] = s[threadIdx.x] - x;
    if (threadIdx.x == 1023) bsums[blockIdx.x] = s[1023];
}

__global__ void scan2_k(int* __restrict__ bsums, int nblocks) {
    if (threadIdx.x == 0 && blockIdx.x == 0) {
        int run = 0;
        for (int b = 0; b < nblocks; ++b) {
            int t = bsums[b];
            bsums[b] = run;
            run += t;
        }
    }
}

__global__ __launch_bounds__(256) void scan3_k(int* __restrict__ start,
                                               int* __restrict__ cursor,
                                               const int* __restrict__ bsums) {
    int i = blockIdx.x * 256 + threadIdx.x;
    if (i < N_NODES) {
        int v = start[i] + bsums[i >> 10];
        start[i] = v;
        cursor[i] = v;
    }
}

// per edge: c[b] = sum_r ea[e,r]*att[r,b] for both layers, packed bf16x4 each
__global__ __launch_bounds__(256) void scatter_k(const int* __restrict__ ei,
                                                 const float* __restrict__ ea,
                                                 const float* __restrict__ att,   // [2,8,4]
                                                 int* __restrict__ cursor,
                                                 int* __restrict__ src_s,
                                                 uint2* __restrict__ c0s,
                                                 uint2* __restrict__ c1s) {
    int e = blockIdx.x * 256 + threadIdx.x;
    if (e >= N_EDGES) return;
    int src = ei[e];
    int dst = ei[N_EDGES + e];

    const float4* eav = (const float4*)(ea + (size_t)e * 8);
    float4 a0 = eav[0], a1 = eav[1];
    float ev[8] = {a0.x, a0.y, a0.z, a0.w, a1.x, a1.y, a1.z, a1.w};

    float4 c0 = make_float4(0.f, 0.f, 0.f, 0.f);
    float4 c1 = make_float4(0.f, 0.f, 0.f, 0.f);
    const float4* att0 = (const float4*)att;
    const float4* att1 = (const float4*)(att + 32);
    #pragma unroll
    for (int r = 0; r < 8; ++r) {
        float4 w0 = att0[r];
        float4 w1 = att1[r];
        c0.x = fmaf(ev[r], w0.x, c0.x); c0.y = fmaf(ev[r], w0.y, c0.y);
        c0.z = fmaf(ev[r], w0.z, c0.z); c0.w = fmaf(ev[r], w0.w, c0.w);
        c1.x = fmaf(ev[r], w1.x, c1.x); c1.y = fmaf(ev[r], w1.y, c1.y);
        c1.z = fmaf(ev[r], w1.z, c1.z); c1.w = fmaf(ev[r], w1.w, c1.w);
    }
    int pos = atomicAdd(&cursor[dst], 1);
    src_s[pos] = src;
    c0s[pos] = make_uint2(pack2(c0.x, c0.y), pack2(c0.z, c0.w));
    c1s[pos] = make_uint2(pack2(c1.x, c1.y), pack2(c1.z, c1.w));
}

// fp32 -> bf16 row copy (x only; h1's bf16 copy is fused into gemm epilogue)
__global__ __launch_bounds__(256) void conv_k(const float* __restrict__ in, ushort* __restrict__ out16, int n8) {
    int i = blockIdx.x * 256 + threadIdx.x;
    if (i >= n8) return;
    const float4* p = (const float4*)(in + (size_t)i * 8);
    float4 a = p[0], b = p[1];
    uint4 o;
    o.x = pack2(a.x, a.y); o.y = pack2(a.z, a.w);
    o.z = pack2(b.x, b.y); o.w = pack2(b.z, b.w);
    *(uint4*)(out16 + (size_t)i * 8) = o;
}

// ---------------- per-layer kernels ----------------

// one wave per dst node; lane = channel. y16[node][b*64+lane] = bf16( sum_e c[e,b]*h16[src][lane] )
__global__ __launch_bounds__(256) void agg_k(const int* __restrict__ start,
                                             const int* __restrict__ counts,
                                             const int* __restrict__ src_s,
                                             const uint2* __restrict__ cs,
                                             const ushort* __restrict__ h16,
                                             ushort* __restrict__ y16) {
    int node = blockIdx.x * 4 + (threadIdx.x >> 6);
    int lane = threadIdx.x & 63;
    if (node >= N_NODES) return;
    int s = start[node];
    int cnt = counts[node];

    float y0 = 0.f, y1 = 0.f, y2 = 0.f, y3 = 0.f;
    int j = 0;
    for (; j + 3 < cnt; j += 4) {
        int e = s + j;
        int s0 = src_s[e], s1 = src_s[e + 1], s2 = src_s[e + 2], s3 = src_s[e + 3];
        uint2 q0 = cs[e], q1 = cs[e + 1], q2 = cs[e + 2], q3 = cs[e + 3];
        float h0 = bf2f(h16[(size_t)s0 * 64 + lane]);
        float h1 = bf2f(h16[(size_t)s1 * 64 + lane]);
        float h2 = bf2f(h16[(size_t)s2 * 64 + lane]);
        float h3 = bf2f(h16[(size_t)s3 * 64 + lane]);
        y0 = fmaf(bf2f((ushort)(q0.x & 0xffff)), h0, y0);
        y1 = fmaf(bf2f((ushort)(q0.x >> 16)),    h0, y1);
        y2 = fmaf(bf2f((ushort)(q0.y & 0xffff)), h0, y2);
        y3 = fmaf(bf2f((ushort)(q0.y >> 16)),    h0, y3);
        y0 = fmaf(bf2f((ushort)(q1.x & 0xffff)), h1, y0);
        y1 = fmaf(bf2f((ushort)(q1.x >> 16)),    h1, y1);
        y2 = fmaf(bf2f((ushort)(q1.y & 0xffff)), h1, y2);
        y3 = fmaf(bf2f((ushort)(q1.y >> 16)),    h1, y3);
        y0 = fmaf(bf2f((ushort)(q2.x & 0xffff)), h2, y0);
        y1 = fmaf(bf2f((ushort)(q2.x >> 16)),    h2, y1);
        y2 = fmaf(bf2f((ushort)(q2.y & 0xffff)), h2, y2);
        y3 = fmaf(bf2f((ushort)(q2.y >> 16)),    h2, y3);
        y0 = fmaf(bf2f((ushort)(q3.x & 0xffff)), h3, y0);
        y1 = fmaf(bf2f((ushort)(q3.x >> 16)),    h3, y1);
        y2 = fmaf(bf2f((ushort)(q3.y & 0xffff)), h3, y2);
        y3 = fmaf(bf2f((ushort)(q3.y >> 16)),    h3, y3);
    }
    for (; j < cnt; ++j) {
        int e = s + j;
        int sv = src_s[e];
        uint2 q = cs[e];
        float hv = bf2f(h16[(size_t)sv * 64 + lane]);
        y0 = fmaf(bf2f((ushort)(q.x & 0xffff)), hv, y0);
        y1 = fmaf(bf2f((ushort)(q.x >> 16)),    hv, y1);
        y2 = fmaf(bf2f((ushort)(q.y & 0xffff)), hv, y2);
        y3 = fmaf(bf2f((ushort)(q.y >> 16)),    hv, y3);
    }
    ushort* yr = y16 + (size_t)node * 256;
    yr[lane]       = f2bf(y0);
    yr[64 + lane]  = f2bf(y1);
    yr[128 + lane] = f2bf(y2);
    yr[192 + lane] = f2bf(y3);
}

// out[64x64 tile] = y16(K=256,bf16)@B + h(K=64,fp32)@root + bias [, relu]
// 256 threads, 4x4 outputs/thread, K via LDS. Optionally writes bf16 copy of out.
__global__ __launch_bounds__(256) void gemm_k(const ushort* __restrict__ y16,
                                              const float* __restrict__ h,
                                              const float* __restrict__ B,
                                              const float* __restrict__ root,
                                              const float* __restrict__ bias,
                                              float* __restrict__ out,
                                              ushort* __restrict__ out16,  // may be null
                                              int relu) {
    __shared__ float As[16][68];
    __shared__ float Bs[16][64];

    const int tid = threadIdx.x;
    const int tx = tid & 15;
    const int ty = tid >> 4;
    const int n0 = blockIdx.x * 64;

    const int sm = tid >> 2;     // A-staging row 0..63
    const int sc = tid & 3;      // A-staging k-group 0..3
    const int skk = tid >> 4;    // W-staging k 0..15
    const int snn = tid & 15;    // W-staging col group

    float acc[4][4];
    #pragma unroll
    for (int i = 0; i < 4; ++i)
        #pragma unroll
        for (int jj = 0; jj < 4; ++jj) acc[i][jj] = 0.f;

    // ---- phase 0: y16 (bf16, lda=256), W = B, 16 chunks ----
    #pragma unroll 1
    for (int ch = 0; ch < 16; ++ch) {
        const int kc = ch * 16;
        __syncthreads();
        {
            int n = n0 + sm;
            float a0 = 0.f, a1 = 0.f, a2 = 0.f, a3 = 0.f;
            if (n < N_NODES) {
                uint2 v = *(const uint2*)(y16 + (size_t)n * 256 + kc + sc * 4);
                a0 = bf2f((ushort)(v.x & 0xffff));
                a1 = bf2f((ushort)(v.x >> 16));
                a2 = bf2f((ushort)(v.y & 0xffff));
                a3 = bf2f((ushort)(v.y >> 16));
            }
            As[sc * 4 + 0][sm] = a0;
            As[sc * 4 + 1][sm] = a1;
            As[sc * 4 + 2][sm] = a2;
            As[sc * 4 + 3][sm] = a3;
        }
        {
            float4 wv = *(const float4*)(B + (size_t)(kc + skk) * 64 + snn * 4);
            *(float4*)&Bs[skk][snn * 4] = wv;
        }
        __syncthreads();
        #pragma unroll
        for (int k = 0; k < 16; ++k) {
            float4 a = *(const float4*)&As[k][ty * 4];
            float4 b = *(const float4*)&Bs[k][tx * 4];
            float af[4] = {a.x, a.y, a.z, a.w};
            float bf[4] = {b.x, b.y, b.z, b.w};
            #pragma unroll
            for (int i = 0; i < 4; ++i)
                #pragma unroll
                for (int jj = 0; jj < 4; ++jj)
                    acc[i][jj] = fmaf(af[i], bf[jj], acc[i][jj]);
        }
    }

    // ---- phase 1: h (fp32, lda=64), W = root, 4 chunks ----
    #pragma unroll 1
    for (int ch = 0; ch < 4; ++ch) {
        const int kc = ch * 16;
        __syncthreads();
        {
            int n = n0 + sm;
            float4 av = (n < N_NODES)
                ? *(const float4*)(h + (size_t)n * 64 + kc + sc * 4)
                : make_float4(0.f, 0.f, 0.f, 0.f);
            As[sc * 4 + 0][sm] = av.x;
            As[sc * 4 + 1][sm] = av.y;
            As[sc * 4 + 2][sm] = av.z;
            As[sc * 4 + 3][sm] = av.w;
        }
        {
            float4 wv = *(const float4*)(root + (size_t)(kc + skk) * 64 + snn * 4);
            *(float4*)&Bs[skk][snn * 4] = wv;
        }
        __syncthreads();
        #pragma unroll
        for (int k = 0; k < 16; ++k) {
            float4 a = *(const float4*)&As[k][ty * 4];
            float4 b = *(const float4*)&Bs[k][tx * 4];
            float af[4] = {a.x, a.y, a.z, a.w};
            float bf[4] = {b.x, b.y, b.z, b.w};
            #pragma unroll
            for (int i = 0; i < 4; ++i)
                #pragma unroll
                for (int jj = 0; jj < 4; ++jj)
                    acc[i][jj] = fmaf(af[i], bf[jj], acc[i][jj]);
        }
    }

    float4 bv = *(const float4*)(bias + tx * 4);
    float bf[4] = {bv.x, bv.y, bv.z, bv.w};
    #pragma unroll
    for (int i = 0; i < 4; ++i) {
        int n = n0 + ty * 4 + i;
        if (n < N_NODES) {
            float4 o;
            o.x = acc[i][0] + bf[0];
            o.y = acc[i][1] + bf[1];
            o.z = acc[i][2] + bf[2];
            o.w = acc[i][3] + bf[3];
            if (relu) {
                o.x = fmaxf(o.x, 0.f); o.y = fmaxf(o.y, 0.f);
                o.z = fmaxf(o.z, 0.f); o.w = fmaxf(o.w, 0.f);
            }
            *(float4*)(out + (size_t)n * 64 + tx * 4) = o;
            if (out16) {
                uint2 p;
                p.x = pack2(o.x, o.y);
                p.y = pack2(o.z, o.w);
                *(uint2*)(out16 + (size_t)n * 64 + tx * 4) = p;
            }
        }
    }
}

// ---------------- launch ----------------

extern "C" void kernel_launch(void* const* d_in, const int* in_sizes, int n_in,
                              void* d_out, int out_size, void* d_ws, size_t ws_size,
                              hipStream_t stream) {
    const float* x     = (const float*)d_in[0];
    const int*   ei    = (const int*)d_in[1];
    const float* ea    = (const float*)d_in[2];
    const float* basis = (const float*)d_in[3];  // [2,4,64,64]
    const float* att   = (const float*)d_in[4];  // [2,8,4]
    const float* root  = (const float*)d_in[5];  // [2,64,64]
    const float* bias  = (const float*)d_in[6];  // [2,64]
    float* out = (float*)d_out;

    char* p = (char*)d_ws;
    ushort* y16    = (ushort*)p;  p += (size_t)N_NODES * 256 * 2;  // 25.6 MB
    ushort* hb16   = (ushort*)p;  p += (size_t)N_NODES * 64 * 2;   //  6.4 MB (x bf16, then h1 bf16)
    int*    src_s  = (int*)p;     p += (size_t)N_EDGES * 4;        //  3.2 MB
    uint2*  c0s    = (uint2*)p;   p += (size_t)N_EDGES * 8;        //  6.4 MB
    uint2*  c1s    = (uint2*)p;   p += (size_t)N_EDGES * 8;        //  6.4 MB
    int*    counts = (int*)p;     p += (size_t)N_NODES * 4;
    int*    start  = (int*)p;     p += (size_t)N_NODES * 4;
    int*    cursor = (int*)p;     p += (size_t)N_NODES * 4;
    int*    bsums  = (int*)p;     p += 64 * 4;

    float* h1 = out;  // layer-0 fp32 output lives in d_out; overwritten by final gemm

    const int scan_blocks = (N_NODES + 1023) / 1024;  // 49

    zero_counts<<<(N_NODES + 255) / 256, 256, 0, stream>>>(counts);
    hist_k<<<(N_EDGES + 255) / 256, 256, 0, stream>>>(ei, counts);
    scan1_k<<<scan_blocks, 1024, 0, stream>>>(counts, start, bsums);
    scan2_k<<<1, 64, 0, stream>>>(bsums, scan_blocks);
    scan3_k<<<(N_NODES + 255) / 256, 256, 0, stream>>>(start, cursor, bsums);
    scatter_k<<<(N_EDGES + 255) / 256, 256, 0, stream>>>(ei, ea, att, cursor, src_s, c0s, c1s);
    conv_k<<<(N_NODES * 64 / 8 + 255) / 256, 256, 0, stream>>>(x, hb16, N_NODES * 64 / 8);

    dim3 agg_grid((N_NODES + 3) / 4);
    dim3 gemm_grid((N_NODES + 63) / 64);

    // ---- layer 0: x -> h1 (relu); gemm also emits h1 bf16 into hb16 ----
    agg_k<<<agg_grid, 256, 0, stream>>>(start, counts, src_s, c0s, hb16, y16);
    gemm_k<<<gemm_grid, 256, 0, stream>>>(y16, x, basis, root, bias, h1, hb16, 1);

    // ---- layer 1: h1 -> out ----
    agg_k<<<agg_grid, 256, 0, stream>>>(start, counts, src_s, c1s, hb16, y16);
    gemm_k<<<gemm_grid, 256, 0, stream>>>(y16, h1, basis + 4 * 4096, root + 4096, bias + 64, out, (ushort*)0, 0);
}

// Round 5
// 341.575 us; speedup vs baseline: 1.7049x; 1.0417x over previous
//
#include <hip/hip_runtime.h>

#define N_NODES 50000
#define N_EDGES 800000

typedef unsigned int uint;
typedef unsigned short ushort;

__device__ __forceinline__ ushort f2bf(float f) {
    uint u = __builtin_bit_cast(uint, f);
    u += 0x7fffu + ((u >> 16) & 1u);      // round-to-nearest-even
    return (ushort)(u >> 16);
}
__device__ __forceinline__ float bf2f(ushort h) {
    uint u = ((uint)h) << 16;
    return __builtin_bit_cast(float, u);
}
__device__ __forceinline__ float bflo(uint w) { return __builtin_bit_cast(float, w << 16); }
__device__ __forceinline__ float bfhi(uint w) { return __builtin_bit_cast(float, w & 0xffff0000u); }
__device__ __forceinline__ uint pack2(float a, float b) {
    return (uint)f2bf(a) | ((uint)f2bf(b) << 16);
}

// ---------------- CSR build ----------------

__global__ __launch_bounds__(256) void zero_counts(int* __restrict__ counts) {
    int i = blockIdx.x * 256 + threadIdx.x;
    if (i < N_NODES) counts[i] = 0;
}

__global__ __launch_bounds__(256) void hist_k(const int* __restrict__ ei, int* __restrict__ counts) {
    int e = blockIdx.x * 256 + threadIdx.x;
    if (e < N_EDGES) atomicAdd(&counts[ei[N_EDGES + e]], 1);
}

__global__ __launch_bounds__(1024) void scan1_k(const int* __restrict__ counts,
                                                int* __restrict__ start,
                                                int* __restrict__ bsums) {
    __shared__ int s[1024];
    int i = blockIdx.x * 1024 + threadIdx.x;
    int x = (i < N_NODES) ? counts[i] : 0;
    s[threadIdx.x] = x;
    __syncthreads();
    for (int off = 1; off < 1024; off <<= 1) {
        int v = (threadIdx.x >= off) ? s[threadIdx.x - off] : 0;
        __syncthreads();
        s[threadIdx.x] += v;
        __syncthreads();
    }
    if (i < N_NODES) start[i] = s[threadIdx.x] - x;
    if (threadIdx.x == 1023) bsums[blockIdx.x] = s[1023];
}

__global__ void scan2_k(int* __restrict__ bsums, int nblocks) {
    if (threadIdx.x == 0 && blockIdx.x == 0) {
        int run = 0;
        for (int b = 0; b < nblocks; ++b) {
            int t = bsums[b];
            bsums[b] = run;
            run += t;
        }
    }
}

__global__ __launch_bounds__(256) void scan3_k(int* __restrict__ start,
                                               int* __restrict__ cursor,
                                               const int* __restrict__ bsums) {
    int i = blockIdx.x * 256 + threadIdx.x;
    if (i < N_NODES) {
        int v = start[i] + bsums[i >> 10];
        start[i] = v;
        cursor[i] = v;
    }
}

// per edge: c[b] = sum_r ea[e,r]*att[r,b] for both layers; scatter ONE 32B record
// rec[pos] = uint4{src, c0lo, c0hi, 0} , uint4{src, c1lo, c1hi, 0}  (adjacent -> same 64B line)
__global__ __launch_bounds__(256) void scatter_k(const int* __restrict__ ei,
                                                 const float* __restrict__ ea,
                                                 const float* __restrict__ att,   // [2,8,4]
                                                 int* __restrict__ cursor,
                                                 uint4* __restrict__ rec) {
    int e = blockIdx.x * 256 + threadIdx.x;
    if (e >= N_EDGES) return;
    int src = ei[e];
    int dst = ei[N_EDGES + e];

    const float4* eav = (const float4*)(ea + (size_t)e * 8);
    float4 a0 = eav[0], a1 = eav[1];
    float ev[8] = {a0.x, a0.y, a0.z, a0.w, a1.x, a1.y, a1.z, a1.w};

    float4 c0 = make_float4(0.f, 0.f, 0.f, 0.f);
    float4 c1 = make_float4(0.f, 0.f, 0.f, 0.f);
    const float4* att0 = (const float4*)att;
    const float4* att1 = (const float4*)(att + 32);
    #pragma unroll
    for (int r = 0; r < 8; ++r) {
        float4 w0 = att0[r];
        float4 w1 = att1[r];
        c0.x = fmaf(ev[r], w0.x, c0.x); c0.y = fmaf(ev[r], w0.y, c0.y);
        c0.z = fmaf(ev[r], w0.z, c0.z); c0.w = fmaf(ev[r], w0.w, c0.w);
        c1.x = fmaf(ev[r], w1.x, c1.x); c1.y = fmaf(ev[r], w1.y, c1.y);
        c1.z = fmaf(ev[r], w1.z, c1.z); c1.w = fmaf(ev[r], w1.w, c1.w);
    }
    int pos = atomicAdd(&cursor[dst], 1);
    rec[2 * (size_t)pos]     = make_uint4((uint)src, pack2(c0.x, c0.y), pack2(c0.z, c0.w), 0u);
    rec[2 * (size_t)pos + 1] = make_uint4((uint)src, pack2(c1.x, c1.y), pack2(c1.z, c1.w), 0u);
}

// fp32 -> bf16 row copy (x only)
__global__ __launch_bounds__(256) void conv_k(const float* __restrict__ in, ushort* __restrict__ out16, int n8) {
    int i = blockIdx.x * 256 + threadIdx.x;
    if (i >= n8) return;
    const float4* p = (const float4*)(in + (size_t)i * 8);
    float4 a = p[0], b = p[1];
    uint4 o;
    o.x = pack2(a.x, a.y); o.y = pack2(a.z, a.w);
    o.z = pack2(b.x, b.y); o.w = pack2(b.z, b.w);
    *(uint4*)(out16 + (size_t)i * 8) = o;
}

// ---------------- per-layer kernels ----------------

// one wave per dst node; lane = channel.
// recs points at the layer's 16B half (stride 2 uint4 per edge).
__global__ __launch_bounds__(256) void agg_k(const int* __restrict__ start,
                                             const int* __restrict__ counts,
                                             const uint4* __restrict__ recs,
                                             const ushort* __restrict__ h16,
                                             ushort* __restrict__ y16) {
    int node = blockIdx.x * 4 + (threadIdx.x >> 6);
    int lane = threadIdx.x & 63;
    if (node >= N_NODES) return;
    int s = start[node];
    int cnt = counts[node];

    float y0 = 0.f, y1 = 0.f, y2 = 0.f, y3 = 0.f;
    int j = 0;
    for (; j + 7 < cnt; j += 8) {
        uint4 r[8];
        #pragma unroll
        for (int i = 0; i < 8; ++i) r[i] = recs[2 * (size_t)(s + j + i)];
        float hv[8];
        #pragma unroll
        for (int i = 0; i < 8; ++i) hv[i] = bf2f(h16[(size_t)r[i].x * 64 + lane]);
        #pragma unroll
        for (int i = 0; i < 8; ++i) {
            y0 = fmaf(bflo(r[i].y), hv[i], y0);
            y1 = fmaf(bfhi(r[i].y), hv[i], y1);
            y2 = fmaf(bflo(r[i].z), hv[i], y2);
            y3 = fmaf(bfhi(r[i].z), hv[i], y3);
        }
    }
    for (; j + 1 < cnt; j += 2) {
        uint4 ra = recs[2 * (size_t)(s + j)];
        uint4 rb = recs[2 * (size_t)(s + j + 1)];
        float ha = bf2f(h16[(size_t)ra.x * 64 + lane]);
        float hb = bf2f(h16[(size_t)rb.x * 64 + lane]);
        y0 = fmaf(bflo(ra.y), ha, y0); y1 = fmaf(bfhi(ra.y), ha, y1);
        y2 = fmaf(bflo(ra.z), ha, y2); y3 = fmaf(bfhi(ra.z), ha, y3);
        y0 = fmaf(bflo(rb.y), hb, y0); y1 = fmaf(bfhi(rb.y), hb, y1);
        y2 = fmaf(bflo(rb.z), hb, y2); y3 = fmaf(bfhi(rb.z), hb, y3);
    }
    if (j < cnt) {
        uint4 r = recs[2 * (size_t)(s + j)];
        float hv = bf2f(h16[(size_t)r.x * 64 + lane]);
        y0 = fmaf(bflo(r.y), hv, y0); y1 = fmaf(bfhi(r.y), hv, y1);
        y2 = fmaf(bflo(r.z), hv, y2); y3 = fmaf(bfhi(r.z), hv, y3);
    }
    ushort* yr = y16 + (size_t)node * 256;
    yr[lane]       = f2bf(y0);
    yr[64 + lane]  = f2bf(y1);
    yr[128 + lane] = f2bf(y2);
    yr[192 + lane] = f2bf(y3);
}

// out[64x64 tile] = y16(K=256,bf16)@B + h(K=64,fp32)@root + bias [, relu]
__global__ __launch_bounds__(256) void gemm_k(const ushort* __restrict__ y16,
                                              const float* __restrict__ h,
                                              const float* __restrict__ B,
                                              const float* __restrict__ root,
                                              const float* __restrict__ bias,
                                              float* __restrict__ out,
                                              ushort* __restrict__ out16,  // may be null
                                              int relu) {
    __shared__ float As[16][68];
    __shared__ float Bs[16][64];

    const int tid = threadIdx.x;
    const int tx = tid & 15;
    const int ty = tid >> 4;
    const int n0 = blockIdx.x * 64;

    const int sm = tid >> 2;
    const int sc = tid & 3;
    const int skk = tid >> 4;
    const int snn = tid & 15;

    float acc[4][4];
    #pragma unroll
    for (int i = 0; i < 4; ++i)
        #pragma unroll
        for (int jj = 0; jj < 4; ++jj) acc[i][jj] = 0.f;

    #pragma unroll 1
    for (int ch = 0; ch < 16; ++ch) {
        const int kc = ch * 16;
        __syncthreads();
        {
            int n = n0 + sm;
            float a0 = 0.f, a1 = 0.f, a2 = 0.f, a3 = 0.f;
            if (n < N_NODES) {
                uint2 v = *(const uint2*)(y16 + (size_t)n * 256 + kc + sc * 4);
                a0 = bflo(v.x); a1 = bfhi(v.x);
                a2 = bflo(v.y); a3 = bfhi(v.y);
            }
            As[sc * 4 + 0][sm] = a0;
            As[sc * 4 + 1][sm] = a1;
            As[sc * 4 + 2][sm] = a2;
            As[sc * 4 + 3][sm] = a3;
        }
        {
            float4 wv = *(const float4*)(B + (size_t)(kc + skk) * 64 + snn * 4);
            *(float4*)&Bs[skk][snn * 4] = wv;
        }
        __syncthreads();
        #pragma unroll
        for (int k = 0; k < 16; ++k) {
            float4 a = *(const float4*)&As[k][ty * 4];
            float4 b = *(const float4*)&Bs[k][tx * 4];
            float af[4] = {a.x, a.y, a.z, a.w};
            float bf[4] = {b.x, b.y, b.z, b.w};
            #pragma unroll
            for (int i = 0; i < 4; ++i)
                #pragma unroll
                for (int jj = 0; jj < 4; ++jj)
                    acc[i][jj] = fmaf(af[i], bf[jj], acc[i][jj]);
        }
    }

    #pragma unroll 1
    for (int ch = 0; ch < 4; ++ch) {
        const int kc = ch * 16;
        __syncthreads();
        {
            int n = n0 + sm;
            float4 av = (n < N_NODES)
                ? *(const float4*)(h + (size_t)n * 64 + kc + sc * 4)
                : make_float4(0.f, 0.f, 0.f, 0.f);
            As[sc * 4 + 0][sm] = av.x;
            As[sc * 4 + 1][sm] = av.y;
            As[sc * 4 + 2][sm] = av.z;
            As[sc * 4 + 3][sm] = av.w;
        }
        {
            float4 wv = *(const float4*)(root + (size_t)(kc + skk) * 64 + snn * 4);
            *(float4*)&Bs[skk][snn * 4] = wv;
        }
        __syncthreads();
        #pragma unroll
        for (int k = 0; k < 16; ++k) {
            float4 a = *(const float4*)&As[k][ty * 4];
            float4 b = *(const float4*)&Bs[k][tx * 4];
            float af[4] = {a.x, a.y, a.z, a.w};
            float bf[4] = {b.x, b.y, b.z, b.w};
            #pragma unroll
            for (int i = 0; i < 4; ++i)
                #pragma unroll
                for (int jj = 0; jj < 4; ++jj)
                    acc[i][jj] = fmaf(af[i], bf[jj], acc[i][jj]);
        }
    }

    float4 bv = *(const float4*)(bias + tx * 4);
    float bf[4] = {bv.x, bv.y, bv.z, bv.w};
    #pragma unroll
    for (int i = 0; i < 4; ++i) {
        int n = n0 + ty * 4 + i;
        if (n < N_NODES) {
            float4 o;
            o.x = acc[i][0] + bf[0];
            o.y = acc[i][1] + bf[1];
            o.z = acc[i][2] + bf[2];
            o.w = acc[i][3] + bf[3];
            if (relu) {
                o.x = fmaxf(o.x, 0.f); o.y = fmaxf(o.y, 0.f);
                o.z = fmaxf(o.z, 0.f); o.w = fmaxf(o.w, 0.f);
            }
            *(float4*)(out + (size_t)n * 64 + tx * 4) = o;
            if (out16) {
                uint2 p;
                p.x = pack2(o.x, o.y);
                p.y = pack2(o.z, o.w);
                *(uint2*)(out16 + (size_t)n * 64 + tx * 4) = p;
            }
        }
    }
}

// ---------------- launch ----------------

extern "C" void kernel_launch(void* const* d_in, const int* in_sizes, int n_in,
                              void* d_out, int out_size, void* d_ws, size_t ws_size,
                              hipStream_t stream) {
    const float* x     = (const float*)d_in[0];
    const int*   ei    = (const int*)d_in[1];
    const float* ea    = (const float*)d_in[2];
    const float* basis = (const float*)d_in[3];  // [2,4,64,64]
    const float* att   = (const float*)d_in[4];  // [2,8,4]
    const float* root  = (const float*)d_in[5];  // [2,64,64]
    const float* bias  = (const float*)d_in[6];  // [2,64]
    float* out = (float*)d_out;

    char* p = (char*)d_ws;
    uint4*  rec    = (uint4*)p;   p += (size_t)N_EDGES * 32;       // 25.6 MB (2 x uint4 per edge)
    ushort* y16    = (ushort*)p;  p += (size_t)N_NODES * 256 * 2;  // 25.6 MB
    ushort* hb16   = (ushort*)p;  p += (size_t)N_NODES * 64 * 2;   //  6.4 MB
    int*    counts = (int*)p;     p += (size_t)N_NODES * 4;
    int*    start  = (int*)p;     p += (size_t)N_NODES * 4;
    int*    cursor = (int*)p;     p += (size_t)N_NODES * 4;
    int*    bsums  = (int*)p;     p += 64 * 4;

    float* h1 = out;  // layer-0 fp32 output lives in d_out; overwritten by final gemm

    const int scan_blocks = (N_NODES + 1023) / 1024;  // 49

    zero_counts<<<(N_NODES + 255) / 256, 256, 0, stream>>>(counts);
    hist_k<<<(N_EDGES + 255) / 256, 256, 0, stream>>>(ei, counts);
    scan1_k<<<scan_blocks, 1024, 0, stream>>>(counts, start, bsums);
    scan2_k<<<1, 64, 0, stream>>>(bsums, scan_blocks);
    scan3_k<<<(N_NODES + 255) / 256, 256, 0, stream>>>(start, cursor, bsums);
    scatter_k<<<(N_EDGES + 255) / 256, 256, 0, stream>>>(ei, ea, att, cursor, rec);
    conv_k<<<(N_NODES * 64 / 8 + 255) / 256, 256, 0, stream>>>(x, hb16, N_NODES * 64 / 8);

    dim3 agg_grid((N_NODES + 3) / 4);
    dim3 gemm_grid((N_NODES + 63) / 64);

    // ---- layer 0: x -> h1 (relu); gemm also emits h1 bf16 into hb16 ----
    agg_k<<<agg_grid, 256, 0, stream>>>(start, counts, rec, hb16, y16);
    gemm_k<<<gemm_grid, 256, 0, stream>>>(y16, x, basis, root, bias, h1, hb16, 1);

    // ---- layer 1: h1 -> out ----
    agg_k<<<agg_grid, 256, 0, stream>>>(start, counts, rec + 1, hb16, y16);
    gemm_k<<<gemm_grid, 256, 0, stream>>>(y16, h1, basis + 4 * 4096, root + 4096, bias + 64, out, (ushort*)0, 0);
}

// Round 6
// 333.315 us; speedup vs baseline: 1.7472x; 1.0248x over previous
//
#include <hip/hip_runtime.h>

#define N_NODES 50000
#define N_EDGES 800000
#define N_PADROWS 50048   // 782 * 64

typedef unsigned int uint;
typedef unsigned short ushort;

typedef __attribute__((ext_vector_type(8))) short short8;
typedef __attribute__((ext_vector_type(4))) float floatx4;

__device__ __forceinline__ ushort f2bf(float f) {
    uint u = __builtin_bit_cast(uint, f);
    u += 0x7fffu + ((u >> 16) & 1u);      // round-to-nearest-even
    return (ushort)(u >> 16);
}
__device__ __forceinline__ float bf2f(ushort h) {
    uint u = ((uint)h) << 16;
    return __builtin_bit_cast(float, u);
}
__device__ __forceinline__ float bflo(uint w) { return __builtin_bit_cast(float, w << 16); }
__device__ __forceinline__ float bfhi(uint w) { return __builtin_bit_cast(float, w & 0xffff0000u); }
__device__ __forceinline__ uint pack2(float a, float b) {
    return (uint)f2bf(a) | ((uint)f2bf(b) << 16);
}

// ---------------- CSR build ----------------

__global__ __launch_bounds__(256) void zero_counts(int* __restrict__ counts) {
    int i = blockIdx.x * 256 + threadIdx.x;
    if (i < N_NODES) counts[i] = 0;
}

__global__ __launch_bounds__(256) void hist_k(const int* __restrict__ ei, int* __restrict__ counts) {
    int e = blockIdx.x * 256 + threadIdx.x;
    if (e < N_EDGES) atomicAdd(&counts[ei[N_EDGES + e]], 1);
}

__global__ __launch_bounds__(1024) void scan1_k(const int* __restrict__ counts,
                                                int* __restrict__ start,
                                                int* __restrict__ bsums) {
    __shared__ int s[1024];
    int i = blockIdx.x * 1024 + threadIdx.x;
    int x = (i < N_NODES) ? counts[i] : 0;
    s[threadIdx.x] = x;
    __syncthreads();
    for (int off = 1; off < 1024; off <<= 1) {
        int v = (threadIdx.x >= off) ? s[threadIdx.x - off] : 0;
        __syncthreads();
        s[threadIdx.x] += v;
        __syncthreads();
    }
    if (i < N_NODES) start[i] = s[threadIdx.x] - x;
    if (threadIdx.x == 1023) bsums[blockIdx.x] = s[1023];
}

__global__ void scan2_k(int* __restrict__ bsums, int nblocks) {
    if (threadIdx.x == 0 && blockIdx.x == 0) {
        int run = 0;
        for (int b = 0; b < nblocks; ++b) {
            int t = bsums[b];
            bsums[b] = run;
            run += t;
        }
    }
}

__global__ __launch_bounds__(256) void scan3_k(int* __restrict__ start,
                                               int* __restrict__ cursor,
                                               const int* __restrict__ bsums) {
    int i = blockIdx.x * 256 + threadIdx.x;
    if (i < N_NODES) {
        int v = start[i] + bsums[i >> 10];
        start[i] = v;
        cursor[i] = v;
    }
}

// scatter ONLY the edge id (4B) -> minimal random-write line traffic
__global__ __launch_bounds__(256) void scatter_k(const int* __restrict__ ei,
                                                 int* __restrict__ cursor,
                                                 int* __restrict__ perm) {
    int e = blockIdx.x * 256 + threadIdx.x;
    if (e >= N_EDGES) return;
    int dst = ei[N_EDGES + e];
    int pos = atomicAdd(&cursor[dst], 1);
    perm[pos] = e;
}

// sequential pass over CSR slots: gather ea[perm[s]], compute both layers' c,
// write src/c0/c1 as dense sequential streams (full-line writes, no amplification)
__global__ __launch_bounds__(256) void reorder_k(const int* __restrict__ perm,
                                                 const int* __restrict__ ei,
                                                 const float* __restrict__ ea,
                                                 const float* __restrict__ att,   // [2,8,4]
                                                 int* __restrict__ src_s,
                                                 uint2* __restrict__ c0s,
                                                 uint2* __restrict__ c1s) {
    int s = blockIdx.x * 256 + threadIdx.x;
    if (s >= N_EDGES) return;
    int e = perm[s];
    int src = ei[e];

    const float4* eav = (const float4*)(ea + (size_t)e * 8);
    float4 a0 = eav[0], a1 = eav[1];
    float ev[8] = {a0.x, a0.y, a0.z, a0.w, a1.x, a1.y, a1.z, a1.w};

    float4 c0 = make_float4(0.f, 0.f, 0.f, 0.f);
    float4 c1 = make_float4(0.f, 0.f, 0.f, 0.f);
    const float4* att0 = (const float4*)att;
    const float4* att1 = (const float4*)(att + 32);
    #pragma unroll
    for (int r = 0; r < 8; ++r) {
        float4 w0 = att0[r];
        float4 w1 = att1[r];
        c0.x = fmaf(ev[r], w0.x, c0.x); c0.y = fmaf(ev[r], w0.y, c0.y);
        c0.z = fmaf(ev[r], w0.z, c0.z); c0.w = fmaf(ev[r], w0.w, c0.w);
        c1.x = fmaf(ev[r], w1.x, c1.x); c1.y = fmaf(ev[r], w1.y, c1.y);
        c1.z = fmaf(ev[r], w1.z, c1.z); c1.w = fmaf(ev[r], w1.w, c1.w);
    }
    src_s[s] = src;
    c0s[s] = make_uint2(pack2(c0.x, c0.y), pack2(c0.z, c0.w));
    c1s[s] = make_uint2(pack2(c1.x, c1.y), pack2(c1.z, c1.w));
}

// x fp32 -> bf16 into yh0's h-section (row stride 320)
__global__ __launch_bounds__(256) void conv_k(const float* __restrict__ in, ushort* __restrict__ yh) {
    int i = blockIdx.x * 256 + threadIdx.x;
    if (i >= N_NODES * 8) return;
    int n = i >> 3, g = i & 7;
    const float4* p = (const float4*)(in + (size_t)n * 64 + g * 8);
    float4 a = p[0], b = p[1];
    uint4 o;
    o.x = pack2(a.x, a.y); o.y = pack2(a.z, a.w);
    o.z = pack2(b.x, b.y); o.w = pack2(b.z, b.w);
    *(uint4*)(yh + (size_t)n * 320 + 256 + g * 8) = o;
}

// Build MFMA-fragment-ordered bf16 weights: Bsw[l][kb][ct][q][n][j] = W_l[kb*32+q*8+j][ct*16+n]
// W_l = [basis_l (256x64) ; root_l (64x64)]
__global__ __launch_bounds__(256) void prep_k(const float* __restrict__ basis,
                                              const float* __restrict__ root,
                                              ushort* __restrict__ Bsw) {
    int idx = blockIdx.x * 256 + threadIdx.x;
    if (idx >= 2 * 20480) return;
    int l = idx / 20480;
    int r = idx % 20480;
    int kb = r >> 11, ct = (r >> 9) & 3, q = (r >> 7) & 3, n = (r >> 3) & 15, j = r & 7;
    int k = kb * 32 + q * 8 + j;
    int c = ct * 16 + n;
    float v = (k < 256) ? basis[(size_t)l * 16384 + k * 64 + c]
                        : root[(size_t)l * 4096 + (k - 256) * 64 + c];
    Bsw[idx] = f2bf(v);
}

// ---------------- per-layer kernels ----------------

// one wave per dst node; lane = channel. Writes y into yh row [0..256); gathers h from [256..320).
__global__ __launch_bounds__(256) void agg_k(const int* __restrict__ start,
                                             const int* __restrict__ counts,
                                             const int* __restrict__ src_s,
                                             const uint2* __restrict__ cs,
                                             const ushort* __restrict__ yh_gather,  // = yh + 256
                                             ushort* __restrict__ yh_write) {       // = yh
    int node = blockIdx.x * 4 + (threadIdx.x >> 6);
    int lane = threadIdx.x & 63;
    if (node >= N_NODES) return;
    int s = start[node];
    int cnt = counts[node];

    float y0 = 0.f, y1 = 0.f, y2 = 0.f, y3 = 0.f;
    int j = 0;
    for (; j + 7 < cnt; j += 8) {
        int sv[8]; uint2 q[8];
        #pragma unroll
        for (int i = 0; i < 8; ++i) sv[i] = src_s[s + j + i];
        #pragma unroll
        for (int i = 0; i < 8; ++i) q[i] = cs[s + j + i];
        float hv[8];
        #pragma unroll
        for (int i = 0; i < 8; ++i) hv[i] = bf2f(yh_gather[(size_t)sv[i] * 320 + lane]);
        #pragma unroll
        for (int i = 0; i < 8; ++i) {
            y0 = fmaf(bflo(q[i].x), hv[i], y0);
            y1 = fmaf(bfhi(q[i].x), hv[i], y1);
            y2 = fmaf(bflo(q[i].y), hv[i], y2);
            y3 = fmaf(bfhi(q[i].y), hv[i], y3);
        }
    }
    for (; j + 1 < cnt; j += 2) {
        int s0 = src_s[s + j], s1 = src_s[s + j + 1];
        uint2 qa = cs[s + j], qb = cs[s + j + 1];
        float ha = bf2f(yh_gather[(size_t)s0 * 320 + lane]);
        float hb = bf2f(yh_gather[(size_t)s1 * 320 + lane]);
        y0 = fmaf(bflo(qa.x), ha, y0); y1 = fmaf(bfhi(qa.x), ha, y1);
        y2 = fmaf(bflo(qa.y), ha, y2); y3 = fmaf(bfhi(qa.y), ha, y3);
        y0 = fmaf(bflo(qb.x), hb, y0); y1 = fmaf(bfhi(qb.x), hb, y1);
        y2 = fmaf(bflo(qb.y), hb, y2); y3 = fmaf(bfhi(qb.y), hb, y3);
    }
    if (j < cnt) {
        int s0 = src_s[s + j];
        uint2 qa = cs[s + j];
        float ha = bf2f(yh_gather[(size_t)s0 * 320 + lane]);
        y0 = fmaf(bflo(qa.x), ha, y0); y1 = fmaf(bfhi(qa.x), ha, y1);
        y2 = fmaf(bflo(qa.y), ha, y2); y3 = fmaf(bfhi(qa.y), ha, y3);
    }
    ushort* yr = yh_write + (size_t)node * 320;
    yr[lane]       = f2bf(y0);
    yr[64 + lane]  = f2bf(y1);
    yr[128 + lane] = f2bf(y2);
    yr[192 + lane] = f2bf(y3);
}

// MFMA GEMM: out[n][c] = sum_{k<320} yh[n][k] * W[k][c] + bias[c]  (A bf16, W bf16, acc fp32)
// One wave computes 16 rows x 64 cols (4 col-tiles). Bsw staged to LDS in fragment order.
__global__ __launch_bounds__(256) void gemm_k(const ushort* __restrict__ yh,     // [N_PADROWS][320] bf16
                                              const ushort* __restrict__ Bsw,   // [2560][8] bf16 fragment order
                                              const float* __restrict__ bias,   // [64]
                                              float* __restrict__ outf,         // fp32 out or null
                                              ushort* __restrict__ out16,       // next yh base or null (h-section)
                                              int relu) {
    __shared__ uint4 bs[2560];   // 40 KB
    const int tid = threadIdx.x;
    for (int i = tid; i < 2560; i += 256) bs[i] = ((const uint4*)Bsw)[i];

    const int lane = tid & 63;
    const int wid = tid >> 6;
    const int nlo = lane & 15;
    const int quad = lane >> 4;
    const int m0 = blockIdx.x * 64 + wid * 16;

    floatx4 acc[4];
    #pragma unroll
    for (int ct = 0; ct < 4; ++ct) acc[ct] = (floatx4){0.f, 0.f, 0.f, 0.f};

    const ushort* arow = yh + (size_t)(m0 + nlo) * 320 + quad * 8;
    __syncthreads();

    #pragma unroll
    for (int kb = 0; kb < 10; ++kb) {
        uint4 av = *(const uint4*)(arow + kb * 32);
        short8 a = __builtin_bit_cast(short8, av);
        #pragma unroll
        for (int ct = 0; ct < 4; ++ct) {
            short8 b = __builtin_bit_cast(short8, bs[(kb * 4 + ct) * 64 + lane]);
            acc[ct] = __builtin_amdgcn_mfma_f32_16x16x32_bf16(a, b, acc[ct], 0, 0, 0);
        }
    }

    // C/D layout: col = lane&15 (within col-tile), row = quad*4 + reg
    #pragma unroll
    for (int ct = 0; ct < 4; ++ct) {
        int col = ct * 16 + nlo;
        float bv = bias[col];
        #pragma unroll
        for (int r = 0; r < 4; ++r) {
            int row = m0 + quad * 4 + r;
            if (row < N_NODES) {
                float v = acc[ct][r] + bv;
                if (relu) v = fmaxf(v, 0.f);
                if (outf)  outf[(size_t)row * 64 + col] = v;
                if (out16) out16[(size_t)row * 320 + 256 + col] = f2bf(v);
            }
        }
    }
}

// ---------------- launch ----------------

extern "C" void kernel_launch(void* const* d_in, const int* in_sizes, int n_in,
                              void* d_out, int out_size, void* d_ws, size_t ws_size,
                              hipStream_t stream) {
    const float* x     = (const float*)d_in[0];
    const int*   ei    = (const int*)d_in[1];
    const float* ea    = (const float*)d_in[2];
    const float* basis = (const float*)d_in[3];  // [2,4,64,64]
    const float* att   = (const float*)d_in[4];  // [2,8,4]
    const float* root  = (const float*)d_in[5];  // [2,64,64]
    const float* bias  = (const float*)d_in[6];  // [2,64]
    float* out = (float*)d_out;

    char* p = (char*)d_ws;
    ushort* yh0    = (ushort*)p;  p += (size_t)N_PADROWS * 320 * 2;  // 32.0 MB
    ushort* yh1    = (ushort*)p;  p += (size_t)N_PADROWS * 320 * 2;  // 32.0 MB
    int*    perm   = (int*)p;     p += (size_t)N_EDGES * 4;          //  3.2 MB
    int*    src_s  = (int*)p;     p += (size_t)N_EDGES * 4;          //  3.2 MB
    uint2*  c0s    = (uint2*)p;   p += (size_t)N_EDGES * 8;          //  6.4 MB
    uint2*  c1s    = (uint2*)p;   p += (size_t)N_EDGES * 8;          //  6.4 MB
    ushort* Bsw    = (ushort*)p;  p += (size_t)2 * 20480 * 2;        //  80 KB
    int*    counts = (int*)p;     p += (size_t)N_NODES * 4;
    int*    start  = (int*)p;     p += (size_t)N_NODES * 4;
    int*    cursor = (int*)p;     p += (size_t)N_NODES * 4;
    int*    bsums  = (int*)p;     p += 64 * 4;

    const int scan_blocks = (N_NODES + 1023) / 1024;  // 49

    zero_counts<<<(N_NODES + 255) / 256, 256, 0, stream>>>(counts);
    hist_k<<<(N_EDGES + 255) / 256, 256, 0, stream>>>(ei, counts);
    scan1_k<<<scan_blocks, 1024, 0, stream>>>(counts, start, bsums);
    scan2_k<<<1, 64, 0, stream>>>(bsums, scan_blocks);
    scan3_k<<<(N_NODES + 255) / 256, 256, 0, stream>>>(start, cursor, bsums);
    scatter_k<<<(N_EDGES + 255) / 256, 256, 0, stream>>>(ei, cursor, perm);
    reorder_k<<<(N_EDGES + 255) / 256, 256, 0, stream>>>(perm, ei, ea, att, src_s, c0s, c1s);
    conv_k<<<(N_NODES * 8 + 255) / 256, 256, 0, stream>>>(x, yh0);
    prep_k<<<(2 * 20480 + 255) / 256, 256, 0, stream>>>(basis, root, Bsw);

    dim3 agg_grid((N_NODES + 3) / 4);
    dim3 gemm_grid(N_PADROWS / 64);   // 782

    // ---- layer 0 ----
    agg_k<<<agg_grid, 256, 0, stream>>>(start, counts, src_s, c0s, yh0 + 256, yh0);
    gemm_k<<<gemm_grid, 256, 0, stream>>>(yh0, Bsw, bias, (float*)0, yh1, 1);

    // ---- layer 1 ----
    agg_k<<<agg_grid, 256, 0, stream>>>(start, counts, src_s, c1s, yh1 + 256, yh1);
    gemm_k<<<gemm_grid, 256, 0, stream>>>(yh1, Bsw + 20480, bias + 64, out, (ushort*)0, 0);
}

// Round 7
// 279.097 us; speedup vs baseline: 2.0866x; 1.1943x over previous
//
#include <hip/hip_runtime.h>

#define N_NODES 50000
#define N_EDGES 800000
#define N_PADROWS 50048   // 782 * 64

typedef unsigned int uint;
typedef unsigned short ushort;

typedef __attribute__((ext_vector_type(8))) short short8;
typedef __attribute__((ext_vector_type(4))) float floatx4;

__device__ __forceinline__ ushort f2bf(float f) {
    uint u = __builtin_bit_cast(uint, f);
    u += 0x7fffu + ((u >> 16) & 1u);      // round-to-nearest-even
    return (ushort)(u >> 16);
}
__device__ __forceinline__ float bf2f(ushort h) {
    uint u = ((uint)h) << 16;
    return __builtin_bit_cast(float, u);
}
__device__ __forceinline__ float bflo(uint w) { return __builtin_bit_cast(float, w << 16); }
__device__ __forceinline__ float bfhi(uint w) { return __builtin_bit_cast(float, w & 0xffff0000u); }
__device__ __forceinline__ uint pack2(float a, float b) {
    return (uint)f2bf(a) | ((uint)f2bf(b) << 16);
}

// ---------------- CSR build ----------------

__global__ __launch_bounds__(256) void zero_counts(int* __restrict__ counts) {
    int i = blockIdx.x * 256 + threadIdx.x;
    if (i < N_NODES) counts[i] = 0;
}

__global__ __launch_bounds__(256) void hist_k(const int* __restrict__ ei, int* __restrict__ counts) {
    int e = blockIdx.x * 256 + threadIdx.x;
    if (e < N_EDGES) atomicAdd(&counts[ei[N_EDGES + e]], 1);
}

__global__ __launch_bounds__(1024) void scan1_k(const int* __restrict__ counts,
                                                int* __restrict__ start,
                                                int* __restrict__ bsums) {
    __shared__ int s[1024];
    int i = blockIdx.x * 1024 + threadIdx.x;
    int x = (i < N_NODES) ? counts[i] : 0;
    s[threadIdx.x] = x;
    __syncthreads();
    for (int off = 1; off < 1024; off <<= 1) {
        int v = (threadIdx.x >= off) ? s[threadIdx.x - off] : 0;
        __syncthreads();
        s[threadIdx.x] += v;
        __syncthreads();
    }
    if (i < N_NODES) start[i] = s[threadIdx.x] - x;
    if (threadIdx.x == 1023) bsums[blockIdx.x] = s[1023];
}

__global__ void scan2_k(int* __restrict__ bsums, int nblocks) {
    if (threadIdx.x == 0 && blockIdx.x == 0) {
        int run = 0;
        for (int b = 0; b < nblocks; ++b) {
            int t = bsums[b];
            bsums[b] = run;
            run += t;
        }
    }
}

__global__ __launch_bounds__(256) void scan3_k(int* __restrict__ start,
                                               int* __restrict__ cursor,
                                               const int* __restrict__ bsums) {
    int i = blockIdx.x * 256 + threadIdx.x;
    if (i < N_NODES) {
        int v = start[i] + bsums[i >> 10];
        start[i] = v;
        cursor[i] = v;
    }
}

// fused: per edge compute both layers' c = ea @ att, scatter ONE 64B-line record pair
// rec[2*pos] = {src, c0lo, c0hi, 0}, rec[2*pos+1] = {src, c1lo, c1hi, 0}
__global__ __launch_bounds__(256) void scatter_k(const int* __restrict__ ei,
                                                 const float* __restrict__ ea,
                                                 const float* __restrict__ att,   // [2,8,4]
                                                 int* __restrict__ cursor,
                                                 uint4* __restrict__ rec) {
    int e = blockIdx.x * 256 + threadIdx.x;
    if (e >= N_EDGES) return;
    int src = ei[e];
    int dst = ei[N_EDGES + e];

    const float4* eav = (const float4*)(ea + (size_t)e * 8);
    float4 a0 = eav[0], a1 = eav[1];
    float ev[8] = {a0.x, a0.y, a0.z, a0.w, a1.x, a1.y, a1.z, a1.w};

    float4 c0 = make_float4(0.f, 0.f, 0.f, 0.f);
    float4 c1 = make_float4(0.f, 0.f, 0.f, 0.f);
    const float4* att0 = (const float4*)att;
    const float4* att1 = (const float4*)(att + 32);
    #pragma unroll
    for (int r = 0; r < 8; ++r) {
        float4 w0 = att0[r];
        float4 w1 = att1[r];
        c0.x = fmaf(ev[r], w0.x, c0.x); c0.y = fmaf(ev[r], w0.y, c0.y);
        c0.z = fmaf(ev[r], w0.z, c0.z); c0.w = fmaf(ev[r], w0.w, c0.w);
        c1.x = fmaf(ev[r], w1.x, c1.x); c1.y = fmaf(ev[r], w1.y, c1.y);
        c1.z = fmaf(ev[r], w1.z, c1.z); c1.w = fmaf(ev[r], w1.w, c1.w);
    }
    int pos = atomicAdd(&cursor[dst], 1);
    rec[2 * (size_t)pos]     = make_uint4((uint)src, pack2(c0.x, c0.y), pack2(c0.z, c0.w), 0u);
    rec[2 * (size_t)pos + 1] = make_uint4((uint)src, pack2(c1.x, c1.y), pack2(c1.z, c1.w), 0u);
}

// x fp32 -> dense bf16 [N][64]
__global__ __launch_bounds__(256) void conv_k(const float* __restrict__ in, ushort* __restrict__ hb) {
    int i = blockIdx.x * 256 + threadIdx.x;
    if (i >= N_NODES * 8) return;
    const float4* p = (const float4*)(in + (size_t)i * 8);
    float4 a = p[0], b = p[1];
    uint4 o;
    o.x = pack2(a.x, a.y); o.y = pack2(a.z, a.w);
    o.z = pack2(b.x, b.y); o.w = pack2(b.z, b.w);
    *(uint4*)(hb + (size_t)i * 8) = o;
}

// Build MFMA-fragment-ordered bf16 weights: Bsw[l][kb][ct][q][n][j] = W_l[kb*32+q*8+j][ct*16+n]
// W_l = [basis_l (256x64) ; root_l (64x64)]
__global__ __launch_bounds__(256) void prep_k(const float* __restrict__ basis,
                                              const float* __restrict__ root,
                                              ushort* __restrict__ Bsw) {
    int idx = blockIdx.x * 256 + threadIdx.x;
    if (idx >= 2 * 20480) return;
    int l = idx / 20480;
    int r = idx % 20480;
    int kb = r >> 11, ct = (r >> 9) & 3, q = (r >> 7) & 3, n = (r >> 3) & 15, j = r & 7;
    int k = kb * 32 + q * 8 + j;
    int c = ct * 16 + n;
    float v = (k < 256) ? basis[(size_t)l * 16384 + k * 64 + c]
                        : root[(size_t)l * 4096 + (k - 256) * 64 + c];
    Bsw[idx] = f2bf(v);
}

// ---------------- per-layer kernels ----------------

// one wave per dst node; lane = channel. recs = rec (+1 for layer 1), stride 2 uint4/edge.
// gathers from dense hb [N][64] bf16 (6.4MB, L2-resident); writes y row [256] bf16.
__global__ __launch_bounds__(256) void agg_k(const int* __restrict__ start,
                                             const int* __restrict__ counts,
                                             const uint4* __restrict__ recs,
                                             const ushort* __restrict__ hb,
                                             ushort* __restrict__ y16) {
    int node = blockIdx.x * 4 + (threadIdx.x >> 6);
    int lane = threadIdx.x & 63;
    if (node >= N_NODES) return;
    int s = start[node];
    int cnt = counts[node];

    float y0 = 0.f, y1 = 0.f, y2 = 0.f, y3 = 0.f;
    int j = 0;
    for (; j + 7 < cnt; j += 8) {
        uint4 r[8];
        #pragma unroll
        for (int i = 0; i < 8; ++i) r[i] = recs[2 * (size_t)(s + j + i)];
        float hv[8];
        #pragma unroll
        for (int i = 0; i < 8; ++i) hv[i] = bf2f(hb[(size_t)r[i].x * 64 + lane]);
        #pragma unroll
        for (int i = 0; i < 8; ++i) {
            y0 = fmaf(bflo(r[i].y), hv[i], y0);
            y1 = fmaf(bfhi(r[i].y), hv[i], y1);
            y2 = fmaf(bflo(r[i].z), hv[i], y2);
            y3 = fmaf(bfhi(r[i].z), hv[i], y3);
        }
    }
    for (; j + 1 < cnt; j += 2) {
        uint4 ra = recs[2 * (size_t)(s + j)];
        uint4 rb = recs[2 * (size_t)(s + j + 1)];
        float ha = bf2f(hb[(size_t)ra.x * 64 + lane]);
        float hbv = bf2f(hb[(size_t)rb.x * 64 + lane]);
        y0 = fmaf(bflo(ra.y), ha, y0); y1 = fmaf(bfhi(ra.y), ha, y1);
        y2 = fmaf(bflo(ra.z), ha, y2); y3 = fmaf(bfhi(ra.z), ha, y3);
        y0 = fmaf(bflo(rb.y), hbv, y0); y1 = fmaf(bfhi(rb.y), hbv, y1);
        y2 = fmaf(bflo(rb.z), hbv, y2); y3 = fmaf(bfhi(rb.z), hbv, y3);
    }
    if (j < cnt) {
        uint4 r = recs[2 * (size_t)(s + j)];
        float hv = bf2f(hb[(size_t)r.x * 64 + lane]);
        y0 = fmaf(bflo(r.y), hv, y0); y1 = fmaf(bfhi(r.y), hv, y1);
        y2 = fmaf(bflo(r.z), hv, y2); y3 = fmaf(bfhi(r.z), hv, y3);
    }
    ushort* yr = y16 + (size_t)node * 256;
    yr[lane]       = f2bf(y0);
    yr[64 + lane]  = f2bf(y1);
    yr[128 + lane] = f2bf(y2);
    yr[192 + lane] = f2bf(y3);
}

// MFMA GEMM: out[n][c] = sum_{k<320} [y16|hb][n][k] * W[k][c] + bias[c]
// One wave computes 16 rows x 64 cols. A: kb 0..7 from y16 [N][256], kb 8..9 from hb [N][64].
__global__ __launch_bounds__(256) void gemm_k(const ushort* __restrict__ y16,   // [N_PADROWS][256] bf16
                                              const ushort* __restrict__ hb,    // [N_PADROWS][64] bf16
                                              const ushort* __restrict__ Bsw,   // [2560][8] bf16 fragment order
                                              const float* __restrict__ bias,   // [64]
                                              float* __restrict__ outf,         // fp32 out or null
                                              ushort* __restrict__ outh,        // next hb (bf16) or null
                                              int relu) {
    __shared__ uint4 bs[2560];   // 40 KB
    const int tid = threadIdx.x;
    for (int i = tid; i < 2560; i += 256) bs[i] = ((const uint4*)Bsw)[i];

    const int lane = tid & 63;
    const int wid = tid >> 6;
    const int nlo = lane & 15;
    const int quad = lane >> 4;
    const int m0 = blockIdx.x * 64 + wid * 16;

    floatx4 acc[4];
    #pragma unroll
    for (int ct = 0; ct < 4; ++ct) acc[ct] = (floatx4){0.f, 0.f, 0.f, 0.f};

    const ushort* yrow = y16 + (size_t)(m0 + nlo) * 256 + quad * 8;
    const ushort* hrow = hb  + (size_t)(m0 + nlo) * 64  + quad * 8;
    __syncthreads();

    #pragma unroll
    for (int kb = 0; kb < 10; ++kb) {
        uint4 av = (kb < 8) ? *(const uint4*)(yrow + kb * 32)
                            : *(const uint4*)(hrow + (kb - 8) * 32);
        short8 a = __builtin_bit_cast(short8, av);
        #pragma unroll
        for (int ct = 0; ct < 4; ++ct) {
            short8 b = __builtin_bit_cast(short8, bs[(kb * 4 + ct) * 64 + lane]);
            acc[ct] = __builtin_amdgcn_mfma_f32_16x16x32_bf16(a, b, acc[ct], 0, 0, 0);
        }
    }

    // C/D layout: col = ct*16 + (lane&15), row = quad*4 + reg
    #pragma unroll
    for (int ct = 0; ct < 4; ++ct) {
        int col = ct * 16 + nlo;
        float bv = bias[col];
        #pragma unroll
        for (int r = 0; r < 4; ++r) {
            int row = m0 + quad * 4 + r;
            if (row < N_NODES) {
                float v = acc[ct][r] + bv;
                if (relu) v = fmaxf(v, 0.f);
                if (outf) outf[(size_t)row * 64 + col] = v;
                if (outh) outh[(size_t)row * 64 + col] = f2bf(v);
            }
        }
    }
}

// ---------------- launch ----------------

extern "C" void kernel_launch(void* const* d_in, const int* in_sizes, int n_in,
                              void* d_out, int out_size, void* d_ws, size_t ws_size,
                              hipStream_t stream) {
    const float* x     = (const float*)d_in[0];
    const int*   ei    = (const int*)d_in[1];
    const float* ea    = (const float*)d_in[2];
    const float* basis = (const float*)d_in[3];  // [2,4,64,64]
    const float* att   = (const float*)d_in[4];  // [2,8,4]
    const float* root  = (const float*)d_in[5];  // [2,64,64]
    const float* bias  = (const float*)d_in[6];  // [2,64]
    float* out = (float*)d_out;

    char* p = (char*)d_ws;
    uint4*  rec    = (uint4*)p;   p += (size_t)N_EDGES * 32;          // 25.6 MB
    ushort* y16    = (ushort*)p;  p += (size_t)N_PADROWS * 256 * 2;   // 25.6 MB
    ushort* hb0    = (ushort*)p;  p += (size_t)N_PADROWS * 64 * 2;    //  6.4 MB (x bf16)
    ushort* hb1    = (ushort*)p;  p += (size_t)N_PADROWS * 64 * 2;    //  6.4 MB (h1 bf16)
    ushort* Bsw    = (ushort*)p;  p += (size_t)2 * 20480 * 2;         //  80 KB
    int*    counts = (int*)p;     p += (size_t)N_NODES * 4;
    int*    start  = (int*)p;     p += (size_t)N_NODES * 4;
    int*    cursor = (int*)p;     p += (size_t)N_NODES * 4;
    int*    bsums  = (int*)p;     p += 64 * 4;

    const int scan_blocks = (N_NODES + 1023) / 1024;  // 49

    zero_counts<<<(N_NODES + 255) / 256, 256, 0, stream>>>(counts);
    hist_k<<<(N_EDGES + 255) / 256, 256, 0, stream>>>(ei, counts);
    scan1_k<<<scan_blocks, 1024, 0, stream>>>(counts, start, bsums);
    scan2_k<<<1, 64, 0, stream>>>(bsums, scan_blocks);
    scan3_k<<<(N_NODES + 255) / 256, 256, 0, stream>>>(start, cursor, bsums);
    scatter_k<<<(N_EDGES + 255) / 256, 256, 0, stream>>>(ei, ea, att, cursor, rec);
    conv_k<<<(N_NODES * 8 + 255) / 256, 256, 0, stream>>>(x, hb0);
    prep_k<<<(2 * 20480 + 255) / 256, 256, 0, stream>>>(basis, root, Bsw);

    dim3 agg_grid((N_NODES + 3) / 4);
    dim3 gemm_grid(N_PADROWS / 64);   // 782

    // ---- layer 0: h = x (hb0) -> h1 bf16 (hb1) ----
    agg_k<<<agg_grid, 256, 0, stream>>>(start, counts, rec, hb0, y16);
    gemm_k<<<gemm_grid, 256, 0, stream>>>(y16, hb0, Bsw, bias, (float*)0, hb1, 1);

    // ---- layer 1: h = h1 (hb1) -> out fp32 ----
    agg_k<<<agg_grid, 256, 0, stream>>>(start, counts, rec + 1, hb1, y16);
    gemm_k<<<gemm_grid, 256, 0, stream>>>(y16, hb1, Bsw + 20480, bias + 64, out, (ushort*)0, 0);
}